// Round 17
// baseline (36.436 us; speedup 1.0000x reference)
//
#include <hip/hip_runtime.h>
#include <math.h>

// Problem constants (from reference):
constexpr int Bn = 1024;
constexpr int S  = 512;
constexpr int H  = 768;
constexpr int D1 = 128;
constexpr int HV = H / 4;     // 192 float4 per feature row
constexpr int HALF = 512;     // examples per pipeline half

// ws layout (floats):
//   gp [Bn][768]   — final span means (single plane)
//   P  [6][Bn][D1] — partial h dots: [0,1]=CLS 384-chunks, [2..5]=CRC 192-chunks

// ---------- R16-exact device bodies, parameterized by example base ----------

// CLS-half head: bid in [0,512): chunk c = bid&1, examples (bid>>1)*4 .. +4
__device__ __forceinline__ void cls_head_fn(
    const float* __restrict__ feat, const float* __restrict__ W1,
    float* __restrict__ P, int bid, int t, char* smem) {
  float (*g)[384] = reinterpret_cast<float (*)[384]>(smem);
  float (*part)[4][D1] = reinterpret_cast<float (*)[4][D1]>(smem + 6144);

  const int c = bid & 1;
  const int e0 = (bid >> 1) * 4;
  const int dglob0 = c * 384;

  for (int i = t; i < 384; i += 256) {
    const int e = i / 96;
    const int j = i % 96;
    float4 v = *reinterpret_cast<const float4*>(
        feat + (size_t)(e0 + e) * S * H + dglob0 + j * 4);
    reinterpret_cast<float4*>(&g[e][0])[j] = v;
  }
  __syncthreads();

  const int k = t & (D1 - 1);
  const int sub = t >> 7;
  const int gofs = sub * 192;
  const float* Wc = W1 + (size_t)(dglob0 + gofs) * D1 + k;

  float a0 = 0.f, a1 = 0.f, a2 = 0.f, a3 = 0.f;
  #pragma unroll 4
  for (int d = 0; d < 192; d += 4) {
    float w0 = Wc[(size_t)(d + 0) * D1];
    float w1 = Wc[(size_t)(d + 1) * D1];
    float w2 = Wc[(size_t)(d + 2) * D1];
    float w3 = Wc[(size_t)(d + 3) * D1];
    float4 g0 = *reinterpret_cast<const float4*>(&g[0][gofs + d]);
    float4 g1 = *reinterpret_cast<const float4*>(&g[1][gofs + d]);
    float4 g2 = *reinterpret_cast<const float4*>(&g[2][gofs + d]);
    float4 g3 = *reinterpret_cast<const float4*>(&g[3][gofs + d]);
    a0 += g0.x * w0 + g0.y * w1 + g0.z * w2 + g0.w * w3;
    a1 += g1.x * w0 + g1.y * w1 + g1.z * w2 + g1.w * w3;
    a2 += g2.x * w0 + g2.y * w1 + g2.z * w2 + g2.w * w3;
    a3 += g3.x * w0 + g3.y * w1 + g3.z * w2 + g3.w * w3;
  }
  part[sub][0][k] = a0;
  part[sub][1][k] = a1;
  part[sub][2][k] = a2;
  part[sub][3][k] = a3;
  __syncthreads();

  if (t < D1) {
    #pragma unroll
    for (int e = 0; e < 4; ++e) {
      P[((size_t)c * Bn + (e0 + e)) * D1 + t] = part[0][e][t] + part[1][e][t];
    }
  }
}

// Pool: 1 example b, 4 waves stride-4 rows, LDS cross-wave reduce -> gp[b].
__device__ __forceinline__ void pool_fn(
    const float* __restrict__ feat, const int* __restrict__ start,
    const int* __restrict__ endp, float* __restrict__ gp, int b, int t,
    char* smem) {
  float4 (*pacc)[3][64] = reinterpret_cast<float4 (*)[3][64]>(smem);
  const int w = t >> 6;
  const int l = t & 63;
  const float4* base =
      reinterpret_cast<const float4*>(feat) + (size_t)b * (S * HV);

  const int s0 = start[b];
  const int s1 = endp[b];

  float4 c0{0,0,0,0}, c1{0,0,0,0}, c2{0,0,0,0};
  float4 d0{0,0,0,0}, d1{0,0,0,0}, d2{0,0,0,0};
  int s = s0 + w;
  for (; s + 4 < s1; s += 8) {
    const float4* r0 = base + (size_t)s * HV;
    const float4* r1 = base + (size_t)(s + 4) * HV;
    float4 u0 = r0[l], u1 = r0[l + 64], u2 = r0[l + 128];
    float4 v0 = r1[l], v1 = r1[l + 64], v2 = r1[l + 128];
    c0.x += u0.x; c0.y += u0.y; c0.z += u0.z; c0.w += u0.w;
    c1.x += u1.x; c1.y += u1.y; c1.z += u1.z; c1.w += u1.w;
    c2.x += u2.x; c2.y += u2.y; c2.z += u2.z; c2.w += u2.w;
    d0.x += v0.x; d0.y += v0.y; d0.z += v0.z; d0.w += v0.w;
    d1.x += v1.x; d1.y += v1.y; d1.z += v1.z; d1.w += v1.w;
    d2.x += v2.x; d2.y += v2.y; d2.z += v2.z; d2.w += v2.w;
  }
  for (; s < s1; s += 4) {
    const float4* r0 = base + (size_t)s * HV;
    float4 u0 = r0[l], u1 = r0[l + 64], u2 = r0[l + 128];
    c0.x += u0.x; c0.y += u0.y; c0.z += u0.z; c0.w += u0.w;
    c1.x += u1.x; c1.y += u1.y; c1.z += u1.z; c1.w += u1.w;
    c2.x += u2.x; c2.y += u2.y; c2.z += u2.z; c2.w += u2.w;
  }
  c0.x += d0.x; c0.y += d0.y; c0.z += d0.z; c0.w += d0.w;
  c1.x += d1.x; c1.y += d1.y; c1.z += d1.z; c1.w += d1.w;
  c2.x += d2.x; c2.y += d2.y; c2.z += d2.z; c2.w += d2.w;
  pacc[w][0][l] = c0;
  pacc[w][1][l] = c1;
  pacc[w][2][l] = c2;
  __syncthreads();

  if (t < 192) {
    const int seg = t >> 6, ln = t & 63;
    float4 a = pacc[0][seg][ln], bb = pacc[1][seg][ln];
    float4 cq = pacc[2][seg][ln], dq = pacc[3][seg][ln];
    const float inv = 1.0f / (float)(s1 - s0);
    float4 r;
    r.x = ((a.x + bb.x) + (cq.x + dq.x)) * inv;
    r.y = ((a.y + bb.y) + (cq.y + dq.y)) * inv;
    r.z = ((a.z + bb.z) + (cq.z + dq.z)) * inv;
    r.w = ((a.w + bb.w) + (cq.w + dq.w)) * inv;
    reinterpret_cast<float4*>(gp)[(size_t)b * HV + t] = r;
  }
}

// CRC head: chunk cc in {0..3}, example group eg (4 examples), 8-deep ILP.
__device__ __forceinline__ void crc_fn(
    const float* __restrict__ gp, const float* __restrict__ W1,
    float* __restrict__ P, int cc, int eg, int t, char* smem) {
  float (*g)[192] = reinterpret_cast<float (*)[192]>(smem);
  float (*part)[4][D1] = reinterpret_cast<float (*)[4][D1]>(smem + 3072);

  const int e0 = eg * 4;
  const int dd04 = cc * 48;

  if (t < 192) {
    const int e = t / 48;
    const int j = t % 48;
    float4 v =
        reinterpret_cast<const float4*>(gp)[(size_t)(e0 + e) * HV + dd04 + j];
    reinterpret_cast<float4*>(&g[e][0])[j] = v;
  }
  __syncthreads();

  const int k = t & (D1 - 1);
  const int sub = t >> 7;
  const int gofs = sub * 96;
  const float* Wc = W1 + (size_t)(H + cc * 192 + gofs) * D1 + k;

  float a0 = 0.f, a1 = 0.f, a2 = 0.f, a3 = 0.f;
  #pragma unroll 2
  for (int d = 0; d < 96; d += 8) {
    float w0 = Wc[(size_t)(d + 0) * D1];
    float w1 = Wc[(size_t)(d + 1) * D1];
    float w2 = Wc[(size_t)(d + 2) * D1];
    float w3 = Wc[(size_t)(d + 3) * D1];
    float w4 = Wc[(size_t)(d + 4) * D1];
    float w5 = Wc[(size_t)(d + 5) * D1];
    float w6 = Wc[(size_t)(d + 6) * D1];
    float w7 = Wc[(size_t)(d + 7) * D1];
    #define ACC8(i)                                                        \
    {                                                                      \
      float4 gA = *reinterpret_cast<const float4*>(&g[i][gofs + d]);       \
      float4 gB = *reinterpret_cast<const float4*>(&g[i][gofs + d + 4]);   \
      a##i += gA.x * w0 + gA.y * w1 + gA.z * w2 + gA.w * w3                \
            + gB.x * w4 + gB.y * w5 + gB.z * w6 + gB.w * w7;               \
    }
    ACC8(0) ACC8(1) ACC8(2) ACC8(3)
    #undef ACC8
  }
  part[sub][0][k] = a0;
  part[sub][1][k] = a1;
  part[sub][2][k] = a2;
  part[sub][3][k] = a3;
  __syncthreads();

  if (t < D1) {
    #pragma unroll
    for (int e = 0; e < 4; ++e) {
      P[((size_t)(2 + cc) * Bn + (e0 + e)) * D1 + t] =
          part[0][e][t] + part[1][e][t];
    }
  }
}

// Finalize: 4 examples starting at e0; wave w owns example; lane l = k-pair.
__device__ __forceinline__ void fin_fn(
    const float* __restrict__ P, const float* __restrict__ b1,
    const float* __restrict__ W2, const float* __restrict__ b2,
    float* __restrict__ out, int e0, int t) {
  const int w = t >> 6, l = t & 63;
  const int e = e0 + w;
  const int k0 = l, k1 = l + 64;
  float h0 = b1[k0], h1 = b1[k1];
  #pragma unroll
  for (int c = 0; c < 6; ++c) {
    h0 += P[((size_t)c * Bn + e) * D1 + k0];
    h1 += P[((size_t)c * Bn + e) * D1 + k1];
  }
  h0 = fmaxf(h0, 0.f); h1 = fmaxf(h1, 0.f);
  float v = h0 * W2[k0] + h1 * W2[k1];
  #pragma unroll
  for (int off = 32; off > 0; off >>= 1) v += __shfl_down(v, off);
  if (l == 0) out[e] = 1.0f / (1.0f + expf(-(v + b2[0])));
}

// ---------------- pipeline stages ----------------

// Stage 1: cls-head(all examples) [512 blocks first] + pool(A) [512].
__global__ __launch_bounds__(256) void stage1(
    const float* __restrict__ feat, const int* __restrict__ start,
    const int* __restrict__ endp, float* __restrict__ gp,
    const float* __restrict__ W1, float* __restrict__ P) {
  __shared__ __align__(16) char smem[12288];
  if (blockIdx.x < 512) {
    cls_head_fn(feat, W1, P, blockIdx.x, threadIdx.x, smem);
  } else {
    pool_fn(feat, start, endp, gp, blockIdx.x - 512, threadIdx.x, smem);
  }
}

// Stage 2: crc(A) [512 blocks first] + pool(B) [512].
__global__ __launch_bounds__(256) void stage2(
    const float* __restrict__ feat, const int* __restrict__ start,
    const int* __restrict__ endp, float* __restrict__ gp,
    const float* __restrict__ W1, float* __restrict__ P) {
  __shared__ __align__(16) char smem[12288];
  if (blockIdx.x < 512) {
    crc_fn(gp, W1, P, blockIdx.x & 3, blockIdx.x >> 2, threadIdx.x, smem);
  } else {
    pool_fn(feat, start, endp, gp, (blockIdx.x - 512) + HALF, threadIdx.x,
            smem);
  }
}

// Stage 3: crc(B) [512 blocks first] + fin(A) [128].
__global__ __launch_bounds__(256) void stage3(
    const float* __restrict__ gp, const float* __restrict__ W1,
    float* __restrict__ P, const float* __restrict__ b1,
    const float* __restrict__ W2, const float* __restrict__ b2,
    float* __restrict__ out) {
  __shared__ __align__(16) char smem[12288];
  if (blockIdx.x < 512) {
    crc_fn(gp, W1, P, blockIdx.x & 3, (blockIdx.x >> 2) + HALF / 4,
           threadIdx.x, smem);
  } else {
    fin_fn(P, b1, W2, b2, out, (blockIdx.x - 512) * 4, threadIdx.x);
  }
}

// Stage 4: fin(B) [128 blocks].
__global__ __launch_bounds__(256) void stage4(
    const float* __restrict__ P, const float* __restrict__ b1,
    const float* __restrict__ W2, const float* __restrict__ b2,
    float* __restrict__ out) {
  fin_fn(P, b1, W2, b2, out, HALF + blockIdx.x * 4, threadIdx.x);
}

extern "C" void kernel_launch(void* const* d_in, const int* in_sizes, int n_in,
                              void* d_out, int out_size, void* d_ws, size_t ws_size,
                              hipStream_t stream) {
  const float* feat = (const float*)d_in[0];   // [B,S,H] fp32
  const int* start  = (const int*)d_in[1];     // [B]
  const int* endp   = (const int*)d_in[2];     // [B]
  const float* W1   = (const float*)d_in[3];   // [2H,D1]
  const float* b1   = (const float*)d_in[4];   // [D1]
  const float* W2   = (const float*)d_in[5];   // [D1,1]
  const float* b2   = (const float*)d_in[6];   // [1]
  float* out = (float*)d_out;                  // [B]

  float* wsf = (float*)d_ws;
  float* gp  = wsf;                            // [Bn][768]
  float* P   = gp + (size_t)Bn * H;            // [6][Bn][D1]

  hipLaunchKernelGGL(stage1, dim3(1024), dim3(256), 0, stream,
                     feat, start, endp, gp, W1, P);
  hipLaunchKernelGGL(stage2, dim3(1024), dim3(256), 0, stream,
                     feat, start, endp, gp, W1, P);
  hipLaunchKernelGGL(stage3, dim3(640), dim3(256), 0, stream,
                     gp, W1, P, b1, W2, b2, out);
  hipLaunchKernelGGL(stage4, dim3(128), dim3(256), 0, stream,
                     P, b1, W2, b2, out);
}

// Round 18
// 34.029 us; speedup vs baseline: 1.0707x; 1.0707x over previous
//
#include <hip/hip_runtime.h>
#include <math.h>

// Problem constants (from reference):
constexpr int Bn = 1024;
constexpr int S  = 512;
constexpr int H  = 768;
constexpr int D1 = 128;
constexpr int HV = H / 4;     // 192 float4 per feature row
constexpr int NH = 512;       // cls-head blocks (first in launch-1 grid)

// ws layout (floats):
//   gp [Bn][768]   — final span means (single plane)
//   P  [6][Bn][D1] — partial h dots: [0,1]=CLS 384-chunks, [2..5]=CRC 192-chunks

// Launch 1: blocks [0,NH) = CLS-half head (R16-exact);
// [NH, NH+3072) = pool, block = (example, column-third).
// Pool block: 4 waves x stride-4 rows; lane owns ONE float4 column of its
// third -> 1 KB/row wave-contiguous reads, 4 rows in flight; LDS reduce.
__global__ __launch_bounds__(256) void fused_pool_clshead(
    const float* __restrict__ feat, const int* __restrict__ start,
    const int* __restrict__ endp, float* __restrict__ gp,
    const float* __restrict__ W1, float* __restrict__ P) {
  __shared__ __align__(16) char smem[10240];   // union: cls 10 KB / pool 4 KB

  const int t = threadIdx.x;

  if (blockIdx.x < NH) {
    // ---- CLS-half head (R16-exact): chunk c in {0,1}, 4 examples ----
    float (*g)[384] = reinterpret_cast<float (*)[384]>(smem);
    float (*part)[4][D1] = reinterpret_cast<float (*)[4][D1]>(smem + 6144);

    const int c = blockIdx.x & 1;
    const int e0 = (blockIdx.x >> 1) * 4;
    const int dglob0 = c * 384;

    for (int i = t; i < 384; i += 256) {
      const int e = i / 96;          // 96 float4 per example-chunk
      const int j = i % 96;
      float4 v = *reinterpret_cast<const float4*>(
          feat + (size_t)(e0 + e) * S * H + dglob0 + j * 4);
      reinterpret_cast<float4*>(&g[e][0])[j] = v;
    }
    __syncthreads();

    const int k = t & (D1 - 1);
    const int sub = t >> 7;
    const int gofs = sub * 192;
    const float* Wc = W1 + (size_t)(dglob0 + gofs) * D1 + k;

    float a0 = 0.f, a1 = 0.f, a2 = 0.f, a3 = 0.f;
    #pragma unroll 4
    for (int d = 0; d < 192; d += 4) {
      float w0 = Wc[(size_t)(d + 0) * D1];
      float w1 = Wc[(size_t)(d + 1) * D1];
      float w2 = Wc[(size_t)(d + 2) * D1];
      float w3 = Wc[(size_t)(d + 3) * D1];
      float4 g0 = *reinterpret_cast<const float4*>(&g[0][gofs + d]);
      float4 g1 = *reinterpret_cast<const float4*>(&g[1][gofs + d]);
      float4 g2 = *reinterpret_cast<const float4*>(&g[2][gofs + d]);
      float4 g3 = *reinterpret_cast<const float4*>(&g[3][gofs + d]);
      a0 += g0.x * w0 + g0.y * w1 + g0.z * w2 + g0.w * w3;
      a1 += g1.x * w0 + g1.y * w1 + g1.z * w2 + g1.w * w3;
      a2 += g2.x * w0 + g2.y * w1 + g2.z * w2 + g2.w * w3;
      a3 += g3.x * w0 + g3.y * w1 + g3.z * w2 + g3.w * w3;
    }
    part[sub][0][k] = a0;
    part[sub][1][k] = a1;
    part[sub][2][k] = a2;
    part[sub][3][k] = a3;
    __syncthreads();

    if (t < D1) {
      #pragma unroll
      for (int e = 0; e < 4; ++e) {
        P[((size_t)c * Bn + (e0 + e)) * D1 + t] = part[0][e][t] + part[1][e][t];
      }
    }
    return;
  }

  // ---- pool: block = (example b, column-third p) ----
  {
    float4 (*pacc)[64] = reinterpret_cast<float4 (*)[64]>(smem);
    const int bb = blockIdx.x - NH;
    const int b = bb / 3;
    const int p = bb - b * 3;        // column-third 0..2
    const int w = t >> 6;            // wave 0..3 (row stride 4)
    const int l = t & 63;            // lane = float4 column within third

    const float4* base4 =
        reinterpret_cast<const float4*>(feat) + (size_t)b * (S * HV) + p * 64;

    const int s0 = start[b];
    const int s1 = endp[b];

    float4 a0{0,0,0,0}, a1{0,0,0,0}, a2{0,0,0,0}, a3{0,0,0,0};
    int s = s0 + w;
    for (; s + 12 < s1; s += 16) {   // 4 of this wave's rows in flight
      float4 v0 = base4[(size_t)(s +  0) * HV + l];
      float4 v1 = base4[(size_t)(s +  4) * HV + l];
      float4 v2 = base4[(size_t)(s +  8) * HV + l];
      float4 v3 = base4[(size_t)(s + 12) * HV + l];
      a0.x += v0.x; a0.y += v0.y; a0.z += v0.z; a0.w += v0.w;
      a1.x += v1.x; a1.y += v1.y; a1.z += v1.z; a1.w += v1.w;
      a2.x += v2.x; a2.y += v2.y; a2.z += v2.z; a2.w += v2.w;
      a3.x += v3.x; a3.y += v3.y; a3.z += v3.z; a3.w += v3.w;
    }
    for (; s < s1; s += 4) {
      float4 v = base4[(size_t)s * HV + l];
      a0.x += v.x; a0.y += v.y; a0.z += v.z; a0.w += v.w;
    }
    float4 r;
    r.x = (a0.x + a1.x) + (a2.x + a3.x);
    r.y = (a0.y + a1.y) + (a2.y + a3.y);
    r.z = (a0.z + a1.z) + (a2.z + a3.z);
    r.w = (a0.w + a1.w) + (a2.w + a3.w);
    pacc[w][l] = r;
    __syncthreads();

    if (t < 64) {
      const float inv = 1.0f / (float)(s1 - s0);
      float4 q0 = pacc[0][t], q1 = pacc[1][t], q2 = pacc[2][t], q3 = pacc[3][t];
      float4 o;
      o.x = ((q0.x + q1.x) + (q2.x + q3.x)) * inv;
      o.y = ((q0.y + q1.y) + (q2.y + q3.y)) * inv;
      o.z = ((q0.z + q1.z) + (q2.z + q3.z)) * inv;
      o.w = ((q0.w + q1.w) + (q2.w + q3.w)) * inv;
      reinterpret_cast<float4*>(gp)[(size_t)b * HV + p * 64 + t] = o;
    }
  }
}

// Launch 2 (R16-exact): CRC head, 4-chunk split, grid 1024, 8-deep ILP.
__global__ __launch_bounds__(256) void crc_head(
    const float* __restrict__ gp, const float* __restrict__ W1,
    float* __restrict__ P) {
  __shared__ float g[4][192];        // 3 KB: 4 examples' 192-row chunk
  __shared__ float part[2][4][D1];   // 4 KB

  const int t = threadIdx.x;
  const int cc = blockIdx.x & 3;     // CRC chunk 0..3
  const int e0 = (blockIdx.x >> 2) * 4;
  const int dd04 = cc * 48;          // chunk offset in float4

  if (t < 192) {
    const int e = t / 48;
    const int j = t % 48;
    float4 v = reinterpret_cast<const float4*>(gp)[(size_t)(e0 + e) * HV + dd04 + j];
    reinterpret_cast<float4*>(&g[e][0])[j] = v;
  }
  __syncthreads();

  const int k = t & (D1 - 1);
  const int sub = t >> 7;            // 96-row half of the chunk
  const int gofs = sub * 96;
  const float* Wc = W1 + (size_t)(H + cc * 192 + gofs) * D1 + k;

  float a0 = 0.f, a1 = 0.f, a2 = 0.f, a3 = 0.f;
  #pragma unroll 2
  for (int d = 0; d < 96; d += 8) {
    float w0 = Wc[(size_t)(d + 0) * D1];
    float w1 = Wc[(size_t)(d + 1) * D1];
    float w2 = Wc[(size_t)(d + 2) * D1];
    float w3 = Wc[(size_t)(d + 3) * D1];
    float w4 = Wc[(size_t)(d + 4) * D1];
    float w5 = Wc[(size_t)(d + 5) * D1];
    float w6 = Wc[(size_t)(d + 6) * D1];
    float w7 = Wc[(size_t)(d + 7) * D1];
    #define ACC8(i)                                                        \
    {                                                                      \
      float4 gA = *reinterpret_cast<const float4*>(&g[i][gofs + d]);       \
      float4 gB = *reinterpret_cast<const float4*>(&g[i][gofs + d + 4]);   \
      a##i += gA.x * w0 + gA.y * w1 + gA.z * w2 + gA.w * w3                \
            + gB.x * w4 + gB.y * w5 + gB.z * w6 + gB.w * w7;               \
    }
    ACC8(0) ACC8(1) ACC8(2) ACC8(3)
    #undef ACC8
  }
  part[sub][0][k] = a0;
  part[sub][1][k] = a1;
  part[sub][2][k] = a2;
  part[sub][3][k] = a3;
  __syncthreads();

  if (t < D1) {
    #pragma unroll
    for (int e = 0; e < 4; ++e) {
      P[((size_t)(2 + cc) * Bn + (e0 + e)) * D1 + t] =
          part[0][e][t] + part[1][e][t];
    }
  }
}

// Launch 3 (R16-exact): combine 6 chunks, relu, W2, sigmoid. 1 wave/example.
__global__ __launch_bounds__(256) void finalize(
    const float* __restrict__ P, const float* __restrict__ b1,
    const float* __restrict__ W2, const float* __restrict__ b2,
    float* __restrict__ out) {
  const int t = threadIdx.x;
  const int w = t >> 6, l = t & 63;
  const int e = blockIdx.x * 4 + w;
  const int k0 = l, k1 = l + 64;
  float h0 = b1[k0], h1 = b1[k1];
  #pragma unroll
  for (int c = 0; c < 6; ++c) {
    h0 += P[((size_t)c * Bn + e) * D1 + k0];
    h1 += P[((size_t)c * Bn + e) * D1 + k1];
  }
  h0 = fmaxf(h0, 0.f); h1 = fmaxf(h1, 0.f);
  float v = h0 * W2[k0] + h1 * W2[k1];
  #pragma unroll
  for (int off = 32; off > 0; off >>= 1) v += __shfl_down(v, off);
  if (l == 0) out[e] = 1.0f / (1.0f + expf(-(v + b2[0])));
}

extern "C" void kernel_launch(void* const* d_in, const int* in_sizes, int n_in,
                              void* d_out, int out_size, void* d_ws, size_t ws_size,
                              hipStream_t stream) {
  const float* feat = (const float*)d_in[0];   // [B,S,H] fp32
  const int* start  = (const int*)d_in[1];     // [B]
  const int* endp   = (const int*)d_in[2];     // [B]
  const float* W1   = (const float*)d_in[3];   // [2H,D1]
  const float* b1   = (const float*)d_in[4];   // [D1]
  const float* W2   = (const float*)d_in[5];   // [D1,1]
  const float* b2   = (const float*)d_in[6];   // [1]
  float* out = (float*)d_out;                  // [B]

  float* wsf = (float*)d_ws;
  float* gp  = wsf;                            // [Bn][768]
  float* P   = gp + (size_t)Bn * H;            // [6][Bn][D1]

  hipLaunchKernelGGL(fused_pool_clshead, dim3(NH + 3 * Bn), dim3(256), 0,
                     stream, feat, start, endp, gp, W1, P);
  hipLaunchKernelGGL(crc_head, dim3(Bn), dim3(256), 0, stream, gp, W1, P);
  hipLaunchKernelGGL(finalize, dim3(Bn / 4), dim3(256), 0, stream,
                     P, b1, W2, b2, out);
}